// Round 7
// baseline (339.625 us; speedup 1.0000x reference)
//
#include <hip/hip_runtime.h>
#include <math.h>

#define B_ 4
#define L_ 5
#define P_ 1024
#define C_ 256
#define TOK (B_ * L_ * P_)   // 20480

// ---- workspace layout (short/float indices) ----
#define PF0_S 0u
#define PF1_S 2097152u
#define PF2_S 2621440u
#define PF3_S 2752512u
#define PF4_S 2785280u        // end 2818048 shorts
#define WTS_F 1409024u        // float idx (== short 2818048): TOK*32
#define POSS_F 2064384u       // float idx: TOK*64  (ends float 3375104)
#define H2_S  10485760u       // TOK*256 shorts
#define W1T_S 17719296u       // 512*256
#define W2T_S 17850368u       // 256*512 (ends 17981440 shorts ≈ 36 MB)

typedef short bf16x8 __attribute__((ext_vector_type(8)));
typedef float f32x4  __attribute__((ext_vector_type(4)));

__device__ __forceinline__ unsigned short f2bf(float f) {
  unsigned u = __float_as_uint(f);
  unsigned r = (u + 0x7fffu + ((u >> 16) & 1u)) >> 16;   // RNE
  return (unsigned short)r;
}
__device__ __forceinline__ float bf2f(unsigned short u) {
  return __uint_as_float((unsigned)u << 16);
}

// Pre-projection as MFMA GEMM: pf[b*HW+hw, d] = sum_c feat[b,c,hw] * eW[c,d].
// B staged on the fly from fp32 eW (c-major: eW[c*32+d]).
__global__ __launch_bounds__(256) void proj_gemm(
    const float* __restrict__ f0, const float* __restrict__ f1,
    const float* __restrict__ f2, const float* __restrict__ f3,
    const float* __restrict__ f4,
    const float* __restrict__ e0W, const float* __restrict__ e1W,
    const float* __restrict__ e2W, const float* __restrict__ e3W,
    const float* __restrict__ e4W,
    unsigned short* __restrict__ pf) {
  constexpr int LDK = 72;
  __shared__ unsigned short Al[64 * LDK];
  __shared__ unsigned short Bl[32 * LDK];
  int blk = blockIdx.x, tid = threadIdx.x;

  const float* feat; const float* eW; int Cl, HW, lt; unsigned pfo;
  if (blk < 1024)      { feat = f0; eW = e0W; Cl = 64;  HW = 16384; pfo = PF0_S; lt = blk; }
  else if (blk < 1280) { feat = f1; eW = e1W; Cl = 128; HW = 4096;  pfo = PF1_S; lt = blk - 1024; }
  else if (blk < 1344) { feat = f2; eW = e2W; Cl = 256; HW = 1024;  pfo = PF2_S; lt = blk - 1280; }
  else if (blk < 1360) { feat = f3; eW = e3W; Cl = 512; HW = 256;   pfo = PF3_S; lt = blk - 1344; }
  else                 { feat = f4; eW = e4W; Cl = 256; HW = 256;   pfo = PF4_S; lt = blk - 1360; }
  int tpb = HW >> 6;
  int b = lt / tpb;
  int hw0 = (lt - b * tpb) * 64;
  const float* fb = feat + (size_t)b * Cl * HW;

  int cl = tid & 63, quad = tid >> 6;
  int w = tid >> 6, lane = tid & 63, q = lane >> 4, ml = lane & 15;

  f32x4 acc0 = (f32x4){0.f, 0.f, 0.f, 0.f};
  f32x4 acc1 = (f32x4){0.f, 0.f, 0.f, 0.f};

  for (int k0 = 0; k0 < Cl; k0 += 64) {
    if (k0) __syncthreads();
    // stage B chunk 32(d) x 64(c) from fp32 eW
    #pragma unroll
    for (int i = 0; i < 8; ++i) {
      int idx = tid + 256 * i;           // 0..2047
      int d = idx >> 6, k = idx & 63;
      Bl[d * LDK + k] = f2bf(eW[(size_t)(k0 + k) * 32 + d]);
    }
    // stage A chunk transposed
    const float* src = fb + (size_t)(k0 + cl) * HW + hw0 + quad * 16;
    float4 v0 = *(const float4*)(src);
    float4 v1 = *(const float4*)(src + 4);
    float4 v2 = *(const float4*)(src + 8);
    float4 v3 = *(const float4*)(src + 12);
    unsigned short* ac = Al + cl;
    int mb = quad * 16;
    ac[(mb + 0)  * LDK] = f2bf(v0.x); ac[(mb + 1)  * LDK] = f2bf(v0.y);
    ac[(mb + 2)  * LDK] = f2bf(v0.z); ac[(mb + 3)  * LDK] = f2bf(v0.w);
    ac[(mb + 4)  * LDK] = f2bf(v1.x); ac[(mb + 5)  * LDK] = f2bf(v1.y);
    ac[(mb + 6)  * LDK] = f2bf(v1.z); ac[(mb + 7)  * LDK] = f2bf(v1.w);
    ac[(mb + 8)  * LDK] = f2bf(v2.x); ac[(mb + 9)  * LDK] = f2bf(v2.y);
    ac[(mb + 10) * LDK] = f2bf(v2.z); ac[(mb + 11) * LDK] = f2bf(v2.w);
    ac[(mb + 12) * LDK] = f2bf(v3.x); ac[(mb + 13) * LDK] = f2bf(v3.y);
    ac[(mb + 14) * LDK] = f2bf(v3.z); ac[(mb + 15) * LDK] = f2bf(v3.w);
    __syncthreads();
    #pragma unroll
    for (int ks = 0; ks < 2; ks++) {
      bf16x8 af = *(const bf16x8*)(Al + (w * 16 + ml) * LDK + ks * 32 + q * 8);
      bf16x8 b0 = *(const bf16x8*)(Bl + ml * LDK + ks * 32 + q * 8);
      bf16x8 b1 = *(const bf16x8*)(Bl + (16 + ml) * LDK + ks * 32 + q * 8);
      acc0 = __builtin_amdgcn_mfma_f32_16x16x32_bf16(af, b0, acc0, 0, 0, 0);
      acc1 = __builtin_amdgcn_mfma_f32_16x16x32_bf16(af, b1, acc1, 0, 0, 0);
    }
  }

  #pragma unroll
  for (int nt = 0; nt < 2; nt++) {
    f32x4 a = nt ? acc1 : acc0;
    int d = nt * 16 + ml;
    #pragma unroll
    for (int rr = 0; rr < 4; rr++) {
      int m = w * 16 + q * 4 + rr;
      pf[pfo + ((size_t)b * HW + hw0 + m) * 32 + d] = f2bf(a[rr]);
    }
  }
}

// Fused LN1 + scores GEMM (N=96, Wc converted on the fly) + softmax/tanh.
// Blocks >= 320 do prep work: copy_x0, W1T, W2T.
// grid 5440 x 256.
__global__ __launch_bounds__(256) void attn_prep(
    const float* __restrict__ x, const float* __restrict__ ref,
    const float* __restrict__ n1g, const float* __restrict__ n1b,
    const float* __restrict__ awW, const float* __restrict__ soW,
    const float* __restrict__ awb, const float* __restrict__ sob,
    const float* __restrict__ f1W, const float* __restrict__ f2W,
    float* __restrict__ out, unsigned short* __restrict__ W1T,
    unsigned short* __restrict__ W2T,
    float* __restrict__ wts, float* __restrict__ poss) {
  constexpr int LDA = 264;
  __shared__ unsigned short Al[64 * LDA];
  __shared__ unsigned short Bl[96 * 72];
  __shared__ float gg[C_], bb[C_];
  int blk = blockIdx.x;
  int tid = threadIdx.x;

  if (blk >= 320) {           // ---- prep blocks ----
    int i = (blk - 320) * 256 + tid;
    if (i < 1048576) {        // out[:,0] = x[:,0]
      int b = i >> 18;
      int r = i & 262143;
      size_t off = (size_t)b * 6 * P_ * C_ + r;
      out[off] = x[off];
    } else {
      i -= 1048576;
      if (i < 131072) {       // W1T[n*256+k] = f1W[k*512+n]
        int n = i >> 8, k = i & 255;
        W1T[i] = f2bf(f1W[k * 512 + n]);
      } else {                // W2T[n*512+k] = f2W[k*256+n]
        int j = i - 131072;
        int n = j >> 9, k = j & 511;
        W2T[j] = f2bf(f2W[k * 256 + n]);
      }
    }
    return;
  }

  int t0 = blk * 64;
  gg[tid] = n1g[tid];
  bb[tid] = n1b[tid];
  __syncthreads();

  // Phase A: LN1 for 64 token rows (8 threads per row, 32 cols each)
  #pragma unroll
  for (int half = 0; half < 2; ++half) {
    int r = half * 32 + (tid >> 3);
    int c0 = (tid & 7) * 32;
    int t = t0 + r;
    int b = t / (L_ * P_);
    int rr_ = t - b * (L_ * P_);
    int l = rr_ >> 10, p = rr_ & 1023;
    const float* xq = x + (((size_t)b * 6 + (l + 1)) * P_ + p) * C_ + c0;
    const float* x0 = x + (((size_t)b * 6) * P_ + p) * C_ + c0;
    float v[32];
    float s = 0.f, s2 = 0.f;
    #pragma unroll
    for (int i = 0; i < 32; i += 4) {
      float4 a = *(const float4*)(xq + i);
      float4 z = *(const float4*)(x0 + i);
      v[i] = a.x + z.x; v[i + 1] = a.y + z.y; v[i + 2] = a.z + z.z; v[i + 3] = a.w + z.w;
      s += v[i] + v[i + 1] + v[i + 2] + v[i + 3];
      s2 += v[i] * v[i] + v[i + 1] * v[i + 1] + v[i + 2] * v[i + 2] + v[i + 3] * v[i + 3];
    }
    #pragma unroll
    for (int off = 1; off < 8; off <<= 1) {
      s += __shfl_xor(s, off);
      s2 += __shfl_xor(s2, off);
    }
    float mean = s * (1.0f / C_);
    float var = s2 * (1.0f / C_) - mean * mean;
    float rs = rsqrtf(var + 1e-5f);
    unsigned short* dst = Al + r * LDA + c0;
    #pragma unroll
    for (int i = 0; i < 32; ++i)
      dst[i] = f2bf((v[i] - mean) * rs * gg[c0 + i] + bb[c0 + i]);
  }

  // Phase B: MFMA, K=256 in 4 chunks; Wc staged on the fly from fp32.
  f32x4 acc[6];
  #pragma unroll
  for (int i = 0; i < 6; ++i) acc[i] = (f32x4){0.f, 0.f, 0.f, 0.f};
  int w = tid >> 6, lane = tid & 63, q = lane >> 4, ml = lane & 15;

  for (int k0 = 0; k0 < 256; k0 += 64) {
    __syncthreads();
    #pragma unroll
    for (int i = 0; i < 24; ++i) {
      int idx = tid + 256 * i;               // 0..6143 = 96 rows x 64
      int n = idx >> 6, k = idx & 63;
      float wv = (n < 32) ? awW[(size_t)(k0 + k) * 32 + n]
                          : soW[(size_t)(k0 + k) * 64 + (n - 32)];
      Bl[n * 72 + k] = f2bf(wv);
    }
    __syncthreads();
    #pragma unroll
    for (int ks = 0; ks < 2; ++ks) {
      bf16x8 af = *(const bf16x8*)(Al + (w * 16 + ml) * LDA + k0 + ks * 32 + q * 8);
      #pragma unroll
      for (int nt = 0; nt < 6; ++nt) {
        bf16x8 bf = *(const bf16x8*)(Bl + (nt * 16 + ml) * 72 + ks * 32 + q * 8);
        acc[nt] = __builtin_amdgcn_mfma_f32_16x16x32_bf16(af, bf, acc[nt], 0, 0, 0);
      }
    }
  }

  // Epilogue: n<32 -> softmax over 4 adjacent lanes; n>=32 -> tanh + ref.
  #pragma unroll
  for (int nt = 0; nt < 6; ++nt) {
    int n = nt * 16 + ml;
    float bv = (n < 32) ? awb[n] : sob[n - 32];
    f32x4 a = acc[nt];
    if (nt < 2) {
      #pragma unroll
      for (int rr = 0; rr < 4; ++rr) {
        float v = a[rr] + bv;
        float m1 = fmaxf(v, __shfl_xor(v, 1));
        float m = fmaxf(m1, __shfl_xor(m1, 2));
        float e = expf(v - m);
        float su = e + __shfl_xor(e, 1);
        su += __shfl_xor(su, 2);
        int t = t0 + w * 16 + q * 4 + rr;
        wts[(size_t)t * 32 + n] = e / su;
      }
    } else {
      int j = n - 32;
      #pragma unroll
      for (int rr = 0; rr < 4; ++rr) {
        float v = a[rr] + bv;
        int t = t0 + w * 16 + q * 4 + rr;
        int b = t / (L_ * P_);
        int p = t & 1023;
        poss[(size_t)t * 64 + j] = tanhf(v) + ref[((size_t)b * P_ + p) * 2 + (j & 1)];
      }
    }
  }
}

// Fused sampling + residual + LN2.  grid TOK/2 x 256 (2 tokens/block).
__global__ __launch_bounds__(256) void sample_ln2(
    const float* __restrict__ x, const unsigned short* __restrict__ pf,
    const float* __restrict__ wts, const float* __restrict__ poss,
    const float* __restrict__ e0b, const float* __restrict__ e1b,
    const float* __restrict__ e2b, const float* __restrict__ e3b,
    const float* __restrict__ e4b,
    const float* __restrict__ n2g, const float* __restrict__ n2b,
    float* __restrict__ out, unsigned short* __restrict__ h2) {
  __shared__ float coef[256];
  __shared__ int   hwid[256];
  __shared__ float ra[4], rb[4];
  int t0 = blockIdx.x * 2;
  int b = t0 / (L_ * P_);
  int r0 = t0 - b * (L_ * P_);
  int l = r0 >> 10;
  int tid = threadIdx.x;

  int Hl; unsigned pfo; const float* eb;
  if (l == 0)      { Hl = 128; pfo = PF0_S; eb = e0b; }
  else if (l == 1) { Hl = 64;  pfo = PF1_S; eb = e1b; }
  else if (l == 2) { Hl = 32;  pfo = PF2_S; eb = e2b; }
  else if (l == 3) { Hl = 16;  pfo = PF3_S; eb = e3b; }
  else             { Hl = 16;  pfo = PF4_S; eb = e4b; }

  if (tid < 64) {
    int tl = tid >> 5, s = tid & 31;
    int t = t0 + tl;
    float aw = wts[(size_t)t * 32 + s];
    float px = poss[(size_t)t * 64 + s * 2 + 0];
    float py = poss[(size_t)t * 64 + s * 2 + 1];
    float Wm = (float)(Hl - 1);
    float gx = fminf(fmaxf((px + 1.0f) * 0.5f * Wm, 0.0f), Wm);
    float gy = fminf(fmaxf((py + 1.0f) * 0.5f * Wm, 0.0f), Wm);
    float x0f = floorf(gx), y0f = floorf(gy);
    int x0 = (int)x0f, y0 = (int)y0f;
    int x1 = min(x0 + 1, Hl - 1), y1 = min(y0 + 1, Hl - 1);
    float wx = gx - x0f, wy = gy - y0f;
    int base = tid * 4;       // == tl*128 + s*4
    hwid[base + 0] = y0 * Hl + x0; coef[base + 0] = aw * (1.f - wx) * (1.f - wy);
    hwid[base + 1] = y0 * Hl + x1; coef[base + 1] = aw * wx * (1.f - wy);
    hwid[base + 2] = y1 * Hl + x0; coef[base + 2] = aw * (1.f - wx) * wy;
    hwid[base + 3] = y1 * Hl + x1; coef[base + 3] = aw * wx * wy;
  }
  __syncthreads();

  int tl = tid >> 7;              // token in block
  int ch0 = (tid & 127) * 2;      // channel pair
  int h = ch0 >> 5, d = ch0 & 31;
  int t = t0 + tl;
  int p = (r0 + tl) & 1023;
  const unsigned short* pfb = pf + pfo + (size_t)b * (Hl * Hl) * 32;
  int cb = tl * 128 + h * 16;
  float acc0 = 0.f, acc1 = 0.f;
  #pragma unroll
  for (int k = 0; k < 16; ++k) {
    float cf = coef[cb + k];
    unsigned uv = *(const unsigned*)(pfb + (size_t)hwid[cb + k] * 32 + d);
    acc0 += cf * bf2f((unsigned short)(uv & 0xffffu));
    acc1 += cf * bf2f((unsigned short)(uv >> 16));
  }

  size_t o = (((size_t)b * 6 + l + 1) * P_ + p) * C_ + ch0;
  float2 xr = *(const float2*)(x + o);
  float v0 = xr.x + acc0 + eb[d];
  float v1 = xr.y + acc1 + eb[d + 1];
  *(float2*)(out + o) = make_float2(v0, v1);

  // LN2: stats over this token's 256 channels (2 waves)
  float sa = v0 + v1, s2 = v0 * v0 + v1 * v1;
  #pragma unroll
  for (int off = 32; off > 0; off >>= 1) {
    sa += __shfl_xor(sa, off);
    s2 += __shfl_xor(s2, off);
  }
  int wv = tid >> 6;
  if ((tid & 63) == 0) { ra[wv] = sa; rb[wv] = s2; }
  __syncthreads();
  float s  = ra[tl * 2] + ra[tl * 2 + 1];
  float ss = rb[tl * 2] + rb[tl * 2 + 1];
  float mean = s * (1.0f / C_);
  float var = ss * (1.0f / C_) - mean * mean;
  float rs = rsqrtf(var + 1e-5f);
  unsigned short h0 = f2bf((v0 - mean) * rs * n2g[ch0] + n2b[ch0]);
  unsigned short h1 = f2bf((v1 - mean) * rs * n2g[ch0 + 1] + n2b[ch0 + 1]);
  *(unsigned*)(h2 + (size_t)t * C_ + ch0) = (unsigned)h0 | ((unsigned)h1 << 16);
}

// Fused MLP: out += gelu(h2 @ W1 + b1) @ W2 + b2.  grid 320 x 256.
// u never hits global: per 64-col u-chunk, GEMM1 -> gelu -> LDS -> GEMM2 K-chunk.
__global__ __launch_bounds__(256) void fused_mlp(
    const unsigned short* __restrict__ h2,
    const unsigned short* __restrict__ W1T, const unsigned short* __restrict__ W2T,
    const float* __restrict__ f1b, const float* __restrict__ f2b,
    float* __restrict__ out) {
  constexpr int LDA = 264;
  constexpr int LDK = 72;
  __shared__ unsigned short Ah[64 * LDA];   // h2 tile 64x256
  __shared__ unsigned short Us[64 * LDK];   // u chunk 64x64
  __shared__ unsigned short Bs[64 * LDK];   // W1T chunk
  int m0 = blockIdx.x * 64, tid = threadIdx.x;
  int w = tid >> 6, lane = tid & 63, q = lane >> 4, ml = lane & 15;

  // stage h2 tile (2048 int4)
  #pragma unroll
  for (int i = 0; i < 8; ++i) {
    int idx = tid + 256 * i;
    int r = idx >> 5, c8 = (idx & 31) * 8;
    *(int4*)(Ah + r * LDA + c8) = *(const int4*)(h2 + (size_t)(m0 + r) * 256 + c8);
  }

  f32x4 acc2[16];
  #pragma unroll
  for (int i = 0; i < 16; ++i) acc2[i] = (f32x4){0.f, 0.f, 0.f, 0.f};

  for (int uc = 0; uc < 8; ++uc) {
    // GEMM1: u-chunk = Ah @ W1T[uc*64 .. +64)
    f32x4 acc1[4];
    #pragma unroll
    for (int i = 0; i < 4; ++i) acc1[i] = (f32x4){0.f, 0.f, 0.f, 0.f};
    for (int k0 = 0; k0 < 256; k0 += 64) {
      __syncthreads();
      #pragma unroll
      for (int i = 0; i < 2; ++i) {
        int idx = tid + 256 * i;            // 0..511 = 64 rows x 8
        int rr = idx >> 3, kc = (idx & 7) * 8;
        *(int4*)(Bs + rr * LDK + kc) =
            *(const int4*)(W1T + (size_t)(uc * 64 + rr) * 256 + k0 + kc);
      }
      __syncthreads();
      #pragma unroll
      for (int ks = 0; ks < 2; ++ks) {
        bf16x8 af = *(const bf16x8*)(Ah + (w * 16 + ml) * LDA + k0 + ks * 32 + q * 8);
        #pragma unroll
        for (int nt = 0; nt < 4; ++nt) {
          bf16x8 bf = *(const bf16x8*)(Bs + (nt * 16 + ml) * LDK + ks * 32 + q * 8);
          acc1[nt] = __builtin_amdgcn_mfma_f32_16x16x32_bf16(af, bf, acc1[nt], 0, 0, 0);
        }
      }
    }
    // gelu + bias -> Us (row-major)
    __syncthreads();
    #pragma unroll
    for (int nt = 0; nt < 4; ++nt) {
      int ucol = nt * 16 + ml;
      float bv = f1b[uc * 64 + ucol];
      #pragma unroll
      for (int rr = 0; rr < 4; ++rr) {
        float v = acc1[nt][rr] + bv;
        v = 0.5f * v * (1.0f + erff(v * 0.70710678118654752f));
        Us[(w * 16 + q * 4 + rr) * LDK + ucol] = f2bf(v);
      }
    }
    __syncthreads();
    // GEMM2 accumulate: K-chunk uc, B streamed from global W2T
    #pragma unroll
    for (int ks = 0; ks < 2; ++ks) {
      bf16x8 af = *(const bf16x8*)(Us + (w * 16 + ml) * LDK + ks * 32 + q * 8);
      #pragma unroll
      for (int nt = 0; nt < 16; ++nt) {
        bf16x8 bf = *(const bf16x8*)(W2T + (size_t)(nt * 16 + ml) * 512 +
                                     uc * 64 + ks * 32 + q * 8);
        acc2[nt] = __builtin_amdgcn_mfma_f32_16x16x32_bf16(af, bf, acc2[nt], 0, 0, 0);
      }
    }
  }

  // epilogue: out[remap(m), n] += acc2 + b2
  #pragma unroll
  for (int nt = 0; nt < 16; ++nt) {
    int n = nt * 16 + ml;
    float bv = f2b[n];
    #pragma unroll
    for (int rr = 0; rr < 4; ++rr) {
      int m = m0 + w * 16 + q * 4 + rr;
      int s = m >> 10;
      int p = m & 1023;
      int bb = s / 5, ll = s - bb * 5;
      size_t o = (((size_t)bb * 6 + ll + 1) * P_ + p) * C_ + n;
      out[o] += acc2[nt][rr] + bv;
    }
  }
}

extern "C" void kernel_launch(void* const* d_in, const int* in_sizes, int n_in,
                              void* d_out, int out_size, void* d_ws, size_t ws_size,
                              hipStream_t stream) {
  const float* x     = (const float*)d_in[0];
  const float* ref   = (const float*)d_in[1];
  const float* feat0 = (const float*)d_in[2];
  const float* feat1 = (const float*)d_in[3];
  const float* feat2 = (const float*)d_in[4];
  const float* feat3 = (const float*)d_in[5];
  const float* feat4 = (const float*)d_in[6];
  const float* n1g   = (const float*)d_in[7];
  const float* n1b   = (const float*)d_in[8];
  const float* awW   = (const float*)d_in[9];
  const float* awb   = (const float*)d_in[10];
  const float* soW   = (const float*)d_in[11];
  const float* sob   = (const float*)d_in[12];
  const float* e0W   = (const float*)d_in[13];
  const float* e0b   = (const float*)d_in[14];
  const float* e1W   = (const float*)d_in[15];
  const float* e1b   = (const float*)d_in[16];
  const float* e2W   = (const float*)d_in[17];
  const float* e2b   = (const float*)d_in[18];
  const float* e3W   = (const float*)d_in[19];
  const float* e3b   = (const float*)d_in[20];
  const float* e4W   = (const float*)d_in[21];
  const float* e4b   = (const float*)d_in[22];
  const float* n2g   = (const float*)d_in[23];
  const float* n2b   = (const float*)d_in[24];
  const float* f1W   = (const float*)d_in[25];
  const float* f1b   = (const float*)d_in[26];
  const float* f2W   = (const float*)d_in[27];
  const float* f2b   = (const float*)d_in[28];

  float* wsf = (float*)d_ws;
  unsigned short* ws16 = (unsigned short*)d_ws;
  unsigned short* pf  = ws16;
  float* wts  = wsf + WTS_F;
  float* poss = wsf + POSS_F;
  unsigned short* h2  = ws16 + H2_S;
  unsigned short* W1T = ws16 + W1T_S;
  unsigned short* W2T = ws16 + W2T_S;
  float* out = (float*)d_out;

  // 1) LN1 + scores + softmax/tanh; blocks>=320: copy_x0 + W1T/W2T prep
  attn_prep<<<5440, 256, 0, stream>>>(x, ref, n1g, n1b, awW, soW, awb, sob,
                                      f1W, f2W, out, W1T, W2T, wts, poss);

  // 2) pre-project feature pyramids via MFMA (B staged from fp32 eW)
  proj_gemm<<<1376, 256, 0, stream>>>(feat0, feat1, feat2, feat3, feat4,
                                      e0W, e1W, e2W, e3W, e4W, pf);

  // 3) sample + residual + LN2 -> out[:,1:], h2
  sample_ln2<<<TOK / 2, 256, 0, stream>>>(x, pf, wts, poss,
                                          e0b, e1b, e2b, e3b, e4b,
                                          n2g, n2b, out, h2);

  // 4) fused MLP: out += gelu(h2@W1+b1)@W2 + b2
  fused_mlp<<<320, 256, 0, stream>>>(h2, W1T, W2T, f1b, f2b, out);
}

// Round 8
// 257.196 us; speedup vs baseline: 1.3205x; 1.3205x over previous
//
#include <hip/hip_runtime.h>
#include <math.h>

#define B_ 4
#define L_ 5
#define P_ 1024
#define C_ 256
#define TOK (B_ * L_ * P_)   // 20480

// ---- workspace layout (short/float indices) ----
#define PF0_S 0u
#define PF1_S 2097152u
#define PF2_S 2621440u
#define PF3_S 2752512u
#define PF4_S 2785280u        // end 2818048 shorts
#define WTS_F 1409024u        // float idx (== short 2818048): TOK*32
#define POSS_F 2064384u       // float idx: TOK*64  (ends float 3375104)
// u (TOK*512 shorts) overlays [0, 10485760) — pf/wts/poss dead when MLP runs
#define U_S   0u
#define H2_S  10485760u       // TOK*256 shorts
#define W1T_S 17719296u       // 512*256
#define W2T_S 17850368u       // 256*512 (ends 17981440 shorts ≈ 36 MB)

typedef short bf16x8 __attribute__((ext_vector_type(8)));
typedef float f32x4  __attribute__((ext_vector_type(4)));

__device__ __forceinline__ unsigned short f2bf(float f) {
  unsigned u = __float_as_uint(f);
  unsigned r = (u + 0x7fffu + ((u >> 16) & 1u)) >> 16;   // RNE
  return (unsigned short)r;
}
__device__ __forceinline__ float bf2f(unsigned short u) {
  return __uint_as_float((unsigned)u << 16);
}

// Pre-projection as MFMA GEMM: pf[b*HW+hw, d] = sum_c feat[b,c,hw] * eW[c,d].
// B staged on the fly from fp32 eW (c-major: eW[c*32+d]).
__global__ __launch_bounds__(256) void proj_gemm(
    const float* __restrict__ f0, const float* __restrict__ f1,
    const float* __restrict__ f2, const float* __restrict__ f3,
    const float* __restrict__ f4,
    const float* __restrict__ e0W, const float* __restrict__ e1W,
    const float* __restrict__ e2W, const float* __restrict__ e3W,
    const float* __restrict__ e4W,
    unsigned short* __restrict__ pf) {
  constexpr int LDK = 72;
  __shared__ unsigned short Al[64 * LDK];
  __shared__ unsigned short Bl[32 * LDK];
  int blk = blockIdx.x, tid = threadIdx.x;

  const float* feat; const float* eW; int Cl, HW, lt; unsigned pfo;
  if (blk < 1024)      { feat = f0; eW = e0W; Cl = 64;  HW = 16384; pfo = PF0_S; lt = blk; }
  else if (blk < 1280) { feat = f1; eW = e1W; Cl = 128; HW = 4096;  pfo = PF1_S; lt = blk - 1024; }
  else if (blk < 1344) { feat = f2; eW = e2W; Cl = 256; HW = 1024;  pfo = PF2_S; lt = blk - 1280; }
  else if (blk < 1360) { feat = f3; eW = e3W; Cl = 512; HW = 256;   pfo = PF3_S; lt = blk - 1344; }
  else                 { feat = f4; eW = e4W; Cl = 256; HW = 256;   pfo = PF4_S; lt = blk - 1360; }
  int tpb = HW >> 6;
  int b = lt / tpb;
  int hw0 = (lt - b * tpb) * 64;
  const float* fb = feat + (size_t)b * Cl * HW;

  int cl = tid & 63, quad = tid >> 6;
  int w = tid >> 6, lane = tid & 63, q = lane >> 4, ml = lane & 15;

  f32x4 acc0 = (f32x4){0.f, 0.f, 0.f, 0.f};
  f32x4 acc1 = (f32x4){0.f, 0.f, 0.f, 0.f};

  for (int k0 = 0; k0 < Cl; k0 += 64) {
    if (k0) __syncthreads();
    // stage B chunk 32(d) x 64(c) from fp32 eW
    #pragma unroll
    for (int i = 0; i < 8; ++i) {
      int idx = tid + 256 * i;           // 0..2047
      int d = idx >> 6, k = idx & 63;
      Bl[d * LDK + k] = f2bf(eW[(size_t)(k0 + k) * 32 + d]);
    }
    // stage A chunk transposed
    const float* src = fb + (size_t)(k0 + cl) * HW + hw0 + quad * 16;
    float4 v0 = *(const float4*)(src);
    float4 v1 = *(const float4*)(src + 4);
    float4 v2 = *(const float4*)(src + 8);
    float4 v3 = *(const float4*)(src + 12);
    unsigned short* ac = Al + cl;
    int mb = quad * 16;
    ac[(mb + 0)  * LDK] = f2bf(v0.x); ac[(mb + 1)  * LDK] = f2bf(v0.y);
    ac[(mb + 2)  * LDK] = f2bf(v0.z); ac[(mb + 3)  * LDK] = f2bf(v0.w);
    ac[(mb + 4)  * LDK] = f2bf(v1.x); ac[(mb + 5)  * LDK] = f2bf(v1.y);
    ac[(mb + 6)  * LDK] = f2bf(v1.z); ac[(mb + 7)  * LDK] = f2bf(v1.w);
    ac[(mb + 8)  * LDK] = f2bf(v2.x); ac[(mb + 9)  * LDK] = f2bf(v2.y);
    ac[(mb + 10) * LDK] = f2bf(v2.z); ac[(mb + 11) * LDK] = f2bf(v2.w);
    ac[(mb + 12) * LDK] = f2bf(v3.x); ac[(mb + 13) * LDK] = f2bf(v3.y);
    ac[(mb + 14) * LDK] = f2bf(v3.z); ac[(mb + 15) * LDK] = f2bf(v3.w);
    __syncthreads();
    #pragma unroll
    for (int ks = 0; ks < 2; ks++) {
      bf16x8 af = *(const bf16x8*)(Al + (w * 16 + ml) * LDK + ks * 32 + q * 8);
      bf16x8 b0 = *(const bf16x8*)(Bl + ml * LDK + ks * 32 + q * 8);
      bf16x8 b1 = *(const bf16x8*)(Bl + (16 + ml) * LDK + ks * 32 + q * 8);
      acc0 = __builtin_amdgcn_mfma_f32_16x16x32_bf16(af, b0, acc0, 0, 0, 0);
      acc1 = __builtin_amdgcn_mfma_f32_16x16x32_bf16(af, b1, acc1, 0, 0, 0);
    }
  }

  #pragma unroll
  for (int nt = 0; nt < 2; nt++) {
    f32x4 a = nt ? acc1 : acc0;
    int d = nt * 16 + ml;
    #pragma unroll
    for (int rr = 0; rr < 4; rr++) {
      int m = w * 16 + q * 4 + rr;
      pf[pfo + ((size_t)b * HW + hw0 + m) * 32 + d] = f2bf(a[rr]);
    }
  }
}

// Fused LN1 + scores GEMM (N=96, Wc converted on the fly) + softmax/tanh.
// Blocks >= 320 do prep work: copy_x0, W1T, W2T.
// grid 5440 x 256.
__global__ __launch_bounds__(256) void attn_prep(
    const float* __restrict__ x, const float* __restrict__ ref,
    const float* __restrict__ n1g, const float* __restrict__ n1b,
    const float* __restrict__ awW, const float* __restrict__ soW,
    const float* __restrict__ awb, const float* __restrict__ sob,
    const float* __restrict__ f1W, const float* __restrict__ f2W,
    float* __restrict__ out, unsigned short* __restrict__ W1T,
    unsigned short* __restrict__ W2T,
    float* __restrict__ wts, float* __restrict__ poss) {
  constexpr int LDA = 264;
  __shared__ unsigned short Al[64 * LDA];
  __shared__ unsigned short Bl[96 * 72];
  __shared__ float gg[C_], bb[C_];
  int blk = blockIdx.x;
  int tid = threadIdx.x;

  if (blk >= 320) {           // ---- prep blocks ----
    int i = (blk - 320) * 256 + tid;
    if (i < 1048576) {        // out[:,0] = x[:,0]
      int b = i >> 18;
      int r = i & 262143;
      size_t off = (size_t)b * 6 * P_ * C_ + r;
      out[off] = x[off];
    } else {
      i -= 1048576;
      if (i < 131072) {       // W1T[n*256+k] = f1W[k*512+n]
        int n = i >> 8, k = i & 255;
        W1T[i] = f2bf(f1W[k * 512 + n]);
      } else {                // W2T[n*512+k] = f2W[k*256+n]
        int j = i - 131072;
        int n = j >> 9, k = j & 511;
        W2T[j] = f2bf(f2W[k * 256 + n]);
      }
    }
    return;
  }

  int t0 = blk * 64;
  gg[tid] = n1g[tid];
  bb[tid] = n1b[tid];
  __syncthreads();

  // Phase A: LN1 for 64 token rows (8 threads per row, 32 cols each)
  #pragma unroll
  for (int half = 0; half < 2; ++half) {
    int r = half * 32 + (tid >> 3);
    int c0 = (tid & 7) * 32;
    int t = t0 + r;
    int b = t / (L_ * P_);
    int rr_ = t - b * (L_ * P_);
    int l = rr_ >> 10, p = rr_ & 1023;
    const float* xq = x + (((size_t)b * 6 + (l + 1)) * P_ + p) * C_ + c0;
    const float* x0 = x + (((size_t)b * 6) * P_ + p) * C_ + c0;
    float v[32];
    float s = 0.f, s2 = 0.f;
    #pragma unroll
    for (int i = 0; i < 32; i += 4) {
      float4 a = *(const float4*)(xq + i);
      float4 z = *(const float4*)(x0 + i);
      v[i] = a.x + z.x; v[i + 1] = a.y + z.y; v[i + 2] = a.z + z.z; v[i + 3] = a.w + z.w;
      s += v[i] + v[i + 1] + v[i + 2] + v[i + 3];
      s2 += v[i] * v[i] + v[i + 1] * v[i + 1] + v[i + 2] * v[i + 2] + v[i + 3] * v[i + 3];
    }
    #pragma unroll
    for (int off = 1; off < 8; off <<= 1) {
      s += __shfl_xor(s, off);
      s2 += __shfl_xor(s2, off);
    }
    float mean = s * (1.0f / C_);
    float var = s2 * (1.0f / C_) - mean * mean;
    float rs = rsqrtf(var + 1e-5f);
    unsigned short* dst = Al + r * LDA + c0;
    #pragma unroll
    for (int i = 0; i < 32; ++i)
      dst[i] = f2bf((v[i] - mean) * rs * gg[c0 + i] + bb[c0 + i]);
  }

  // Phase B: MFMA, K=256 in 4 chunks; Wc staged on the fly from fp32.
  f32x4 acc[6];
  #pragma unroll
  for (int i = 0; i < 6; ++i) acc[i] = (f32x4){0.f, 0.f, 0.f, 0.f};
  int w = tid >> 6, lane = tid & 63, q = lane >> 4, ml = lane & 15;

  for (int k0 = 0; k0 < 256; k0 += 64) {
    __syncthreads();
    #pragma unroll
    for (int i = 0; i < 24; ++i) {
      int idx = tid + 256 * i;               // 0..6143 = 96 rows x 64
      int n = idx >> 6, k = idx & 63;
      float wv = (n < 32) ? awW[(size_t)(k0 + k) * 32 + n]
                          : soW[(size_t)(k0 + k) * 64 + (n - 32)];
      Bl[n * 72 + k] = f2bf(wv);
    }
    __syncthreads();
    #pragma unroll
    for (int ks = 0; ks < 2; ++ks) {
      bf16x8 af = *(const bf16x8*)(Al + (w * 16 + ml) * LDA + k0 + ks * 32 + q * 8);
      #pragma unroll
      for (int nt = 0; nt < 6; ++nt) {
        bf16x8 bf = *(const bf16x8*)(Bl + (nt * 16 + ml) * 72 + ks * 32 + q * 8);
        acc[nt] = __builtin_amdgcn_mfma_f32_16x16x32_bf16(af, bf, acc[nt], 0, 0, 0);
      }
    }
  }

  // Epilogue: n<32 -> softmax over 4 adjacent lanes; n>=32 -> tanh + ref.
  #pragma unroll
  for (int nt = 0; nt < 6; ++nt) {
    int n = nt * 16 + ml;
    float bv = (n < 32) ? awb[n] : sob[n - 32];
    f32x4 a = acc[nt];
    if (nt < 2) {
      #pragma unroll
      for (int rr = 0; rr < 4; ++rr) {
        float v = a[rr] + bv;
        float m1 = fmaxf(v, __shfl_xor(v, 1));
        float m = fmaxf(m1, __shfl_xor(m1, 2));
        float e = expf(v - m);
        float su = e + __shfl_xor(e, 1);
        su += __shfl_xor(su, 2);
        int t = t0 + w * 16 + q * 4 + rr;
        wts[(size_t)t * 32 + n] = e / su;
      }
    } else {
      int j = n - 32;
      #pragma unroll
      for (int rr = 0; rr < 4; ++rr) {
        float v = a[rr] + bv;
        int t = t0 + w * 16 + q * 4 + rr;
        int b = t / (L_ * P_);
        int p = t & 1023;
        poss[(size_t)t * 64 + j] = tanhf(v) + ref[((size_t)b * P_ + p) * 2 + (j & 1)];
      }
    }
  }
}

// Fused sampling + residual + LN2.  grid TOK/2 x 256 (2 tokens/block).
__global__ __launch_bounds__(256) void sample_ln2(
    const float* __restrict__ x, const unsigned short* __restrict__ pf,
    const float* __restrict__ wts, const float* __restrict__ poss,
    const float* __restrict__ e0b, const float* __restrict__ e1b,
    const float* __restrict__ e2b, const float* __restrict__ e3b,
    const float* __restrict__ e4b,
    const float* __restrict__ n2g, const float* __restrict__ n2b,
    float* __restrict__ out, unsigned short* __restrict__ h2) {
  __shared__ float coef[256];
  __shared__ int   hwid[256];
  __shared__ float ra[4], rb[4];
  int t0 = blockIdx.x * 2;
  int b = t0 / (L_ * P_);
  int r0 = t0 - b * (L_ * P_);
  int l = r0 >> 10;
  int tid = threadIdx.x;

  int Hl; unsigned pfo; const float* eb;
  if (l == 0)      { Hl = 128; pfo = PF0_S; eb = e0b; }
  else if (l == 1) { Hl = 64;  pfo = PF1_S; eb = e1b; }
  else if (l == 2) { Hl = 32;  pfo = PF2_S; eb = e2b; }
  else if (l == 3) { Hl = 16;  pfo = PF3_S; eb = e3b; }
  else             { Hl = 16;  pfo = PF4_S; eb = e4b; }

  if (tid < 64) {
    int tl = tid >> 5, s = tid & 31;
    int t = t0 + tl;
    float aw = wts[(size_t)t * 32 + s];
    float px = poss[(size_t)t * 64 + s * 2 + 0];
    float py = poss[(size_t)t * 64 + s * 2 + 1];
    float Wm = (float)(Hl - 1);
    float gx = fminf(fmaxf((px + 1.0f) * 0.5f * Wm, 0.0f), Wm);
    float gy = fminf(fmaxf((py + 1.0f) * 0.5f * Wm, 0.0f), Wm);
    float x0f = floorf(gx), y0f = floorf(gy);
    int x0 = (int)x0f, y0 = (int)y0f;
    int x1 = min(x0 + 1, Hl - 1), y1 = min(y0 + 1, Hl - 1);
    float wx = gx - x0f, wy = gy - y0f;
    int base = tid * 4;       // == tl*128 + s*4
    hwid[base + 0] = y0 * Hl + x0; coef[base + 0] = aw * (1.f - wx) * (1.f - wy);
    hwid[base + 1] = y0 * Hl + x1; coef[base + 1] = aw * wx * (1.f - wy);
    hwid[base + 2] = y1 * Hl + x0; coef[base + 2] = aw * (1.f - wx) * wy;
    hwid[base + 3] = y1 * Hl + x1; coef[base + 3] = aw * wx * wy;
  }
  __syncthreads();

  int tl = tid >> 7;              // token in block
  int ch0 = (tid & 127) * 2;      // channel pair
  int h = ch0 >> 5, d = ch0 & 31;
  int t = t0 + tl;
  int p = (r0 + tl) & 1023;
  const unsigned short* pfb = pf + pfo + (size_t)b * (Hl * Hl) * 32;
  int cb = tl * 128 + h * 16;
  float acc0 = 0.f, acc1 = 0.f;
  #pragma unroll
  for (int k = 0; k < 16; ++k) {
    float cf = coef[cb + k];
    unsigned uv = *(const unsigned*)(pfb + (size_t)hwid[cb + k] * 32 + d);
    acc0 += cf * bf2f((unsigned short)(uv & 0xffffu));
    acc1 += cf * bf2f((unsigned short)(uv >> 16));
  }

  size_t o = (((size_t)b * 6 + l + 1) * P_ + p) * C_ + ch0;
  float2 xr = *(const float2*)(x + o);
  float v0 = xr.x + acc0 + eb[d];
  float v1 = xr.y + acc1 + eb[d + 1];
  *(float2*)(out + o) = make_float2(v0, v1);

  // LN2: stats over this token's 256 channels (2 waves)
  float sa = v0 + v1, s2 = v0 * v0 + v1 * v1;
  #pragma unroll
  for (int off = 32; off > 0; off >>= 1) {
    sa += __shfl_xor(sa, off);
    s2 += __shfl_xor(s2, off);
  }
  int wv = tid >> 6;
  if ((tid & 63) == 0) { ra[wv] = sa; rb[wv] = s2; }
  __syncthreads();
  float s  = ra[tl * 2] + ra[tl * 2 + 1];
  float ss = rb[tl * 2] + rb[tl * 2 + 1];
  float mean = s * (1.0f / C_);
  float var = ss * (1.0f / C_) - mean * mean;
  float rs = rsqrtf(var + 1e-5f);
  unsigned short h0 = f2bf((v0 - mean) * rs * n2g[ch0] + n2b[ch0]);
  unsigned short h1 = f2bf((v1 - mean) * rs * n2g[ch0 + 1] + n2b[ch0 + 1]);
  *(unsigned*)(h2 + (size_t)t * C_ + ch0) = (unsigned)h0 | ((unsigned)h1 << 16);
}

// bf16 MFMA GEMM, 64x64 tile, BK=64.  A:(M,K) bf16.  Bt:(N,K) bf16.
// MODE 0: outU = bf16(gelu(acc+bias))  MODE 1: outF[remap] += acc+bias
template<int MODE>
__global__ __launch_bounds__(256) void gemm_bf16(
    const unsigned short* __restrict__ A, const unsigned short* __restrict__ Bt,
    const float* __restrict__ bias, unsigned short* __restrict__ outU,
    float* __restrict__ outF, int N, int K) {
  constexpr int LDK = 72;
  __shared__ unsigned short Al[64 * LDK];
  __shared__ unsigned short Bl[64 * LDK];
  int m0 = blockIdx.x * 64, n0 = blockIdx.y * 64;
  int tid = threadIdx.x;
  int w = tid >> 6, lane = tid & 63;
  int q = lane >> 4, ml = lane & 15;
  int lr = tid >> 3;
  int lk = (tid & 7) * 8;

  f32x4 acc[4];
  #pragma unroll
  for (int i = 0; i < 4; i++) acc[i] = (f32x4){0.f, 0.f, 0.f, 0.f};

  for (int k0 = 0; k0 < K; k0 += 64) {
    int4 a0 = *(const int4*)(A + (size_t)(m0 + lr) * K + k0 + lk);
    int4 a1 = *(const int4*)(A + (size_t)(m0 + 32 + lr) * K + k0 + lk);
    int4 b0 = *(const int4*)(Bt + (size_t)(n0 + lr) * K + k0 + lk);
    int4 b1 = *(const int4*)(Bt + (size_t)(n0 + 32 + lr) * K + k0 + lk);
    __syncthreads();
    *(int4*)(Al + lr * LDK + lk) = a0;
    *(int4*)(Al + (32 + lr) * LDK + lk) = a1;
    *(int4*)(Bl + lr * LDK + lk) = b0;
    *(int4*)(Bl + (32 + lr) * LDK + lk) = b1;
    __syncthreads();
    #pragma unroll
    for (int ks = 0; ks < 2; ks++) {
      bf16x8 af = *(const bf16x8*)(Al + (w * 16 + ml) * LDK + ks * 32 + q * 8);
      #pragma unroll
      for (int nt = 0; nt < 4; nt++) {
        bf16x8 bf = *(const bf16x8*)(Bl + (nt * 16 + ml) * LDK + ks * 32 + q * 8);
        acc[nt] = __builtin_amdgcn_mfma_f32_16x16x32_bf16(af, bf, acc[nt], 0, 0, 0);
      }
    }
  }

  #pragma unroll
  for (int nt = 0; nt < 4; nt++) {
    int n = n0 + nt * 16 + ml;
    float bv = bias[n];
    #pragma unroll
    for (int rr = 0; rr < 4; rr++) {
      int m = m0 + w * 16 + q * 4 + rr;
      float v = acc[nt][rr] + bv;
      if (MODE == 0) {
        v = 0.5f * v * (1.0f + erff(v * 0.70710678118654752f));
        outU[(size_t)m * N + n] = f2bf(v);
      } else {
        int s = m >> 10;
        int p = m & 1023;
        int bb = s / 5, ll = s - bb * 5;
        size_t o = (((size_t)bb * 6 + ll + 1) * P_ + p) * C_ + n;
        outF[o] += v;
      }
    }
  }
}

extern "C" void kernel_launch(void* const* d_in, const int* in_sizes, int n_in,
                              void* d_out, int out_size, void* d_ws, size_t ws_size,
                              hipStream_t stream) {
  const float* x     = (const float*)d_in[0];
  const float* ref   = (const float*)d_in[1];
  const float* feat0 = (const float*)d_in[2];
  const float* feat1 = (const float*)d_in[3];
  const float* feat2 = (const float*)d_in[4];
  const float* feat3 = (const float*)d_in[5];
  const float* feat4 = (const float*)d_in[6];
  const float* n1g   = (const float*)d_in[7];
  const float* n1b   = (const float*)d_in[8];
  const float* awW   = (const float*)d_in[9];
  const float* awb   = (const float*)d_in[10];
  const float* soW   = (const float*)d_in[11];
  const float* sob   = (const float*)d_in[12];
  const float* e0W   = (const float*)d_in[13];
  const float* e0b   = (const float*)d_in[14];
  const float* e1W   = (const float*)d_in[15];
  const float* e1b   = (const float*)d_in[16];
  const float* e2W   = (const float*)d_in[17];
  const float* e2b   = (const float*)d_in[18];
  const float* e3W   = (const float*)d_in[19];
  const float* e3b   = (const float*)d_in[20];
  const float* e4W   = (const float*)d_in[21];
  const float* e4b   = (const float*)d_in[22];
  const float* n2g   = (const float*)d_in[23];
  const float* n2b   = (const float*)d_in[24];
  const float* f1W   = (const float*)d_in[25];
  const float* f1b   = (const float*)d_in[26];
  const float* f2W   = (const float*)d_in[27];
  const float* f2b   = (const float*)d_in[28];

  float* wsf = (float*)d_ws;
  unsigned short* ws16 = (unsigned short*)d_ws;
  unsigned short* pf  = ws16;
  float* wts  = wsf + WTS_F;
  float* poss = wsf + POSS_F;
  unsigned short* u   = ws16 + U_S;    // overlays pf/wts/poss (dead by MLP)
  unsigned short* h2  = ws16 + H2_S;
  unsigned short* W1T = ws16 + W1T_S;
  unsigned short* W2T = ws16 + W2T_S;
  float* out = (float*)d_out;

  // 1) LN1 + scores + softmax/tanh; blocks>=320: copy_x0 + W1T/W2T prep
  attn_prep<<<5440, 256, 0, stream>>>(x, ref, n1g, n1b, awW, soW, awb, sob,
                                      f1W, f2W, out, W1T, W2T, wts, poss);

  // 2) pre-project feature pyramids via MFMA (B staged from fp32 eW)
  proj_gemm<<<1376, 256, 0, stream>>>(feat0, feat1, feat2, feat3, feat4,
                                      e0W, e1W, e2W, e3W, e4W, pf);

  // 3) sample + residual + LN2 -> out[:,1:], h2
  sample_ln2<<<TOK / 2, 256, 0, stream>>>(x, pf, wts, poss,
                                          e0b, e1b, e2b, e3b, e4b,
                                          n2g, n2b, out, h2);

  // 4) MLP GEMM1: u = gelu(h2 @ W1 + b1)   (M=20480, N=512, K=256)
  gemm_bf16<0><<<dim3(320, 8), 256, 0, stream>>>(h2, W1T, f1b, u, nullptr, 512, 256);

  // 5) MLP GEMM2: out += u @ W2 + b2       (M=20480, N=256, K=512)
  gemm_bf16<1><<<dim3(320, 4), 256, 0, stream>>>(u, W2T, f2b, nullptr, out, 256, 512);
}